// Round 1
// baseline (587.120 us; speedup 1.0000x reference)
//
#include <hip/hip_runtime.h>

#define N_PTS 81920
#define M_PTS 20000
#define NC 13
#define NCELLS 2197
#define CELLW 0.7692307692f
#define INVCELL 1.3f
#define BIGF 3.0e38f

__device__ __forceinline__ int clampi(int v, int lo, int hi) {
  return v < lo ? lo : (v > hi ? hi : v);
}

__device__ __forceinline__ int cell_coord(float p) {
  return clampi((int)(p * INVCELL), 0, NC - 1);
}

__global__ void zero_kernel(int* __restrict__ p, int n) {
  int i = blockIdx.x * blockDim.x + threadIdx.x;
  if (i < n) p[i] = 0;
}

__global__ void hist_kernel(const float* __restrict__ pts, int n, int* __restrict__ cnt) {
  int i = blockIdx.x * blockDim.x + threadIdx.x;
  if (i >= n) return;
  int cx = cell_coord(pts[3*i]);
  int cy = cell_coord(pts[3*i+1]);
  int cz = cell_coord(pts[3*i+2]);
  atomicAdd(&cnt[(cz*NC + cy)*NC + cx], 1);
}

__global__ void scan_kernel(const int* __restrict__ cnt, int n,
                            int* __restrict__ start, int* __restrict__ cursor) {
  __shared__ int tmp[1024];
  int tid = threadIdx.x;
  int chunk = (n + 1023) >> 10;
  int base = tid * chunk;
  int sum = 0;
  for (int k = 0; k < chunk; ++k) {
    int j = base + k;
    if (j < n) sum += cnt[j];
  }
  tmp[tid] = sum;
  __syncthreads();
  for (int off = 1; off < 1024; off <<= 1) {
    int v = (tid >= off) ? tmp[tid - off] : 0;
    __syncthreads();
    tmp[tid] += v;
    __syncthreads();
  }
  int run = tmp[tid] - sum;
  for (int k = 0; k < chunk; ++k) {
    int j = base + k;
    if (j < n) { start[j] = run; cursor[j] = run; run += cnt[j]; }
  }
  if (tid == 1023) start[n] = tmp[1023];
}

__global__ void scatter_y_kernel(const float* __restrict__ y, int* __restrict__ cursor,
                                 float4* __restrict__ ys4) {
  int i = blockIdx.x * blockDim.x + threadIdx.x;
  if (i >= M_PTS) return;
  float px = y[3*i], py = y[3*i+1], pz = y[3*i+2];
  int c = (cell_coord(pz)*NC + cell_coord(py))*NC + cell_coord(px);
  int pos = atomicAdd(&cursor[c], 1);
  ys4[pos] = make_float4(px, py, pz, __int_as_float(i));
}

// Restore determinism: sort each cell's slice by original index (atomic scatter
// order varies run-to-run; in-cell sort makes ys4 bitwise-identical every call).
__global__ void sortcell_kernel(float4* __restrict__ ys4, const int* __restrict__ ystart) {
  int c = blockIdx.x * blockDim.x + threadIdx.x;
  if (c >= NCELLS) return;
  int r0 = ystart[c], r1 = ystart[c+1];
  for (int i = r0 + 1; i < r1; ++i) {
    float4 v = ys4[i];
    int key = __float_as_int(v.w);
    int j = i - 1;
    while (j >= r0 && __float_as_int(ys4[j].w) > key) { ys4[j+1] = ys4[j]; --j; }
    ys4[j+1] = v;
  }
}

__global__ void scatter_x_kernel(const float* __restrict__ x, int* __restrict__ cursor,
                                 int* __restrict__ xorder) {
  int i = blockIdx.x * blockDim.x + threadIdx.x;
  if (i >= N_PTS) return;
  int c = (cell_coord(x[3*i+2])*NC + cell_coord(x[3*i+1]))*NC + cell_coord(x[3*i]);
  int pos = atomicAdd(&cursor[c], 1);
  xorder[pos] = i;
}

// ---- shared device helpers ----

// LDS layout (floats): W1t[16][20] (i=0..16 incl. invd row), W2t[16][16],
// W3t[16][32], b1, b2, b3, S1, T1, S2, T2  -> 1200 floats
__device__ __forceinline__ void stage_weights(float* lds, int t,
    const float* W1, const float* b1, const float* W2, const float* b2,
    const float* W3, const float* b3,
    const float* g1, const float* be1, const float* m1, const float* v1,
    const float* g2, const float* be2, const float* m2, const float* v2)
{
  for (int k = t; k < 272; k += 256) { int i = k >> 4, o = k & 15; lds[o*20 + i] = W1[k]; }
  for (int k = t; k < 256; k += 256) { int i = k >> 4, o = k & 15; lds[320 + o*16 + i] = W2[k]; }
  for (int k = t; k < 512; k += 256) { int i = k >> 4, o = k & 15; lds[576 + o*32 + i] = W3[k]; }
  if (t < 16) {
    lds[1088 + t] = b1[t];
    lds[1104 + t] = b2[t];
    lds[1120 + t] = b3[t];
    float s1 = g1[t] * rsqrtf(v1[t] + 1e-5f);
    lds[1136 + t] = s1;
    lds[1152 + t] = be1[t] - m1[t]*s1;
    float s2 = g2[t] * rsqrtf(v2[t] + 1e-5f);
    lds[1168 + t] = s2;
    lds[1184 + t] = be2[t] - m2[t]*s2;
  }
}

// Sorted top-16 insert, fully unrolled (static register indices only).
// Caller guarantees d < s[15].
__device__ __forceinline__ void topk_insert(float (&s)[16], int (&si)[16], float d, int qi) {
  #pragma unroll
  for (int j = 15; j >= 1; --j) {
    bool c1 = d < s[j-1];
    bool c2 = d < s[j];
    float ns = c1 ? s[j-1] : (c2 ? d : s[j]);
    int  ni = c1 ? si[j-1] : (c2 ? qi : si[j]);
    s[j] = ns; si[j] = ni;
  }
  if (d < s[0]) { si[0] = qi; s[0] = d; }
}

// spill: per-thread (dist, idx-bits) pairs in LDS, layout [j*256 + t] so the
// rolled neighbor loop can index dynamically without pushing s[]/si[] to scratch.
__device__ __forceinline__ void mlp_and_store(const float* lds, const float2* spill, int t,
    const float* __restrict__ yat, float* __restrict__ out, int p)
{
  const float* W1t = lds;
  const float* W2t = lds + 320;
  const float* W3t = lds + 576;
  const float* sb1 = lds + 1088;
  const float* sb2 = lds + 1104;
  const float* sb3 = lds + 1120;
  const float* S1 = lds + 1136;
  const float* T1 = lds + 1152;
  const float* S2 = lds + 1168;
  const float* T2 = lds + 1184;

  float fx1[16], fx2[16];
  #pragma unroll
  for (int o = 0; o < 16; ++o) { fx1[o] = 0.0f; fx2[o] = 0.0f; }

  #pragma unroll 1
  for (int j = 0; j < 16; ++j) {
    float2 sv = spill[j*256 + t];
    float invd = 1.0f / sv.x;       // reference feature is 1/(squared dist)
    int id = __float_as_int(sv.y);
    const float4* a4 = (const float4*)(yat + ((size_t)id << 4));
    float4 q0 = a4[0], q1 = a4[1], q2 = a4[2], q3 = a4[3];
    float a[16];
    a[0]=q0.x; a[1]=q0.y; a[2]=q0.z; a[3]=q0.w;
    a[4]=q1.x; a[5]=q1.y; a[6]=q1.z; a[7]=q1.w;
    a[8]=q2.x; a[9]=q2.y; a[10]=q2.z; a[11]=q2.w;
    a[12]=q3.x; a[13]=q3.y; a[14]=q3.z; a[15]=q3.w;
    float h[16];
    #pragma unroll
    for (int o = 0; o < 16; ++o) {
      float acc = fmaf(invd, W1t[o*20 + 16], sb1[o]);
      #pragma unroll
      for (int i = 0; i < 16; ++i) acc = fmaf(a[i], W1t[o*20 + i], acc);
      acc = fmaxf(acc, 0.2f * acc);           // leaky_relu(0.2)
      float hv = fmaf(acc, S1[o], T1[o]);     // folded BN1
      h[o] = hv;
      fx1[o] += hv;
    }
    #pragma unroll
    for (int o = 0; o < 16; ++o) {
      float acc = sb2[o];
      #pragma unroll
      for (int i = 0; i < 16; ++i) acc = fmaf(h[i], W2t[o*16 + i], acc);
      acc = fmaxf(acc, 0.2f * acc);
      fx2[o] += fmaf(acc, S2[o], T2[o]);      // folded BN2
    }
  }

  float res[16];
  #pragma unroll
  for (int o = 0; o < 16; ++o) {
    float acc = sb3[o];
    #pragma unroll
    for (int i = 0; i < 16; ++i) acc = fmaf(fx1[i], W3t[o*32 + i], acc);
    #pragma unroll
    for (int i = 0; i < 16; ++i) acc = fmaf(fx2[i], W3t[o*32 + 16 + i], acc);
    res[o] = acc;
  }
  float* op = out + ((size_t)p << 4);
  float4 r;
  r.x=res[0]; r.y=res[1]; r.z=res[2]; r.w=res[3];   ((float4*)op)[0] = r;
  r.x=res[4]; r.y=res[5]; r.z=res[6]; r.w=res[7];   ((float4*)op)[1] = r;
  r.x=res[8]; r.y=res[9]; r.z=res[10]; r.w=res[11]; ((float4*)op)[2] = r;
  r.x=res[12]; r.y=res[13]; r.z=res[14]; r.w=res[15];((float4*)op)[3] = r;
}

// ---- main fused kernel: grid kNN (exact, ring-expansion bound) + MLP ----
__global__ void __launch_bounds__(256) knn_mlp_kernel(
    const float* __restrict__ x, const float* __restrict__ yat,
    const float* __restrict__ W1, const float* __restrict__ b1,
    const float* __restrict__ W2, const float* __restrict__ b2,
    const float* __restrict__ W3, const float* __restrict__ b3,
    const float* __restrict__ g1, const float* __restrict__ be1,
    const float* __restrict__ m1, const float* __restrict__ v1,
    const float* __restrict__ g2, const float* __restrict__ be2,
    const float* __restrict__ m2, const float* __restrict__ v2,
    const float4* __restrict__ ys4, const int* __restrict__ ystart,
    const int* __restrict__ xorder, float* __restrict__ out)
{
  __shared__ float lds[1200];
  __shared__ float2 spill[4096];
  int t = threadIdx.x;
  stage_weights(lds, t, W1,b1,W2,b2,W3,b3, g1,be1,m1,v1, g2,be2,m2,v2);
  __syncthreads();

  int gid = blockIdx.x * 256 + t;   // grid is exactly N_PTS/256
  int p = xorder[gid];
  float xpx = x[3*p], xpy = x[3*p+1], xpz = x[3*p+2];
  int cx = cell_coord(xpx), cy = cell_coord(xpy), cz = cell_coord(xpz);

  float s[16]; int si[16];
  #pragma unroll
  for (int j = 0; j < 16; ++j) { s[j] = BIGF; si[j] = 0; }

  auto scan_row = [&](int gz, int gy, int xa, int xb) {
    int rowbase = (gz*NC + gy)*NC;
    int r0 = ystart[rowbase + xa];
    int r1 = ystart[rowbase + xb + 1];
    for (int i = r0; i < r1; ++i) {
      float4 q = ys4[i];
      float dx = xpx - q.x, dy = xpy - q.y, dz = xpz - q.z;
      float d = fmaf(dx, dx, fmaf(dy, dy, dz*dz));
      if (d < s[15]) topk_insert(s, si, d, __float_as_int(q.w));
    }
  };

  { // initial 3x3x3 (clamped); contiguous x-cells scanned as one range
    int z0 = cz-1 < 0 ? 0 : cz-1, z1 = cz+1 > NC-1 ? NC-1 : cz+1;
    int y0 = cy-1 < 0 ? 0 : cy-1, y1 = cy+1 > NC-1 ? NC-1 : cy+1;
    int x0 = cx-1 < 0 ? 0 : cx-1, x1 = cx+1 > NC-1 ? NC-1 : cx+1;
    for (int gz = z0; gz <= z1; ++gz)
      for (int gy = y0; gy <= y1; ++gy)
        scan_row(gz, gy, x0, x1);
  }

  int R = 1;
  while (true) {
    // distance from x to nearest UNexamined cell (inf where clamped at domain)
    float b = BIGF;
    if (cx - R >= 0)    b = fminf(b, xpx - (float)(cx-R)*CELLW);
    if (cx + R <= NC-2) b = fminf(b, (float)(cx+R+1)*CELLW - xpx);
    if (cy - R >= 0)    b = fminf(b, xpy - (float)(cy-R)*CELLW);
    if (cy + R <= NC-2) b = fminf(b, (float)(cy+R+1)*CELLW - xpy);
    if (cz - R >= 0)    b = fminf(b, xpz - (float)(cz-R)*CELLW);
    if (cz + R <= NC-2) b = fminf(b, (float)(cz+R+1)*CELLW - xpz);
    b = fmaxf(b - 1e-4f, 0.0f);   // conservative vs binning rounding
    if (s[15] <= b*b || R >= NC) break;
    ++R;
    int z0 = cz-R < 0 ? 0 : cz-R, z1 = cz+R > NC-1 ? NC-1 : cz+R;
    int y0 = cy-R < 0 ? 0 : cy-R, y1 = cy+R > NC-1 ? NC-1 : cy+R;
    int x0 = cx-R < 0 ? 0 : cx-R, x1 = cx+R > NC-1 ? NC-1 : cx+R;
    for (int gz = z0; gz <= z1; ++gz) {
      int dzz = gz - cz; if (dzz < 0) dzz = -dzz;
      for (int gy = y0; gy <= y1; ++gy) {
        int dyy = gy - cy; if (dyy < 0) dyy = -dyy;
        if (dzz == R || dyy == R) {
          scan_row(gz, gy, x0, x1);
        } else {
          if (cx - R >= 0)    scan_row(gz, gy, cx-R, cx-R);
          if (cx + R <= NC-1) scan_row(gz, gy, cx+R, cx+R);
        }
      }
    }
  }

  #pragma unroll
  for (int j = 0; j < 16; ++j) spill[j*256 + t] = make_float2(s[j], __int_as_float(si[j]));
  mlp_and_store(lds, spill, t, yat, out, p);
}

// ---- fallback: brute force (no workspace needed) ----
__global__ void __launch_bounds__(256) brute_kernel(
    const float* __restrict__ x, const float* __restrict__ y, const float* __restrict__ yat,
    const float* __restrict__ W1, const float* __restrict__ b1,
    const float* __restrict__ W2, const float* __restrict__ b2,
    const float* __restrict__ W3, const float* __restrict__ b3,
    const float* __restrict__ g1, const float* __restrict__ be1,
    const float* __restrict__ m1, const float* __restrict__ v1,
    const float* __restrict__ g2, const float* __restrict__ be2,
    const float* __restrict__ m2, const float* __restrict__ v2,
    float* __restrict__ out)
{
  __shared__ float lds[1200];
  __shared__ float2 spill[4096];
  __shared__ float4 ybuf[1024];
  int t = threadIdx.x;
  stage_weights(lds, t, W1,b1,W2,b2,W3,b3, g1,be1,m1,v1, g2,be2,m2,v2);

  int gid = blockIdx.x * 256 + t;
  float xpx = x[3*gid], xpy = x[3*gid+1], xpz = x[3*gid+2];
  float s[16]; int si[16];
  #pragma unroll
  for (int j = 0; j < 16; ++j) { s[j] = BIGF; si[j] = 0; }

  for (int base = 0; base < M_PTS; base += 1024) {
    int nload = M_PTS - base; if (nload > 1024) nload = 1024;
    __syncthreads();
    for (int k = t; k < nload; k += 256) {
      int i = base + k;
      ybuf[k] = make_float4(y[3*i], y[3*i+1], y[3*i+2], __int_as_float(i));
    }
    __syncthreads();
    for (int i2 = 0; i2 < nload; ++i2) {
      float4 q = ybuf[i2];
      float dx = xpx - q.x, dy = xpy - q.y, dz = xpz - q.z;
      float d = fmaf(dx, dx, fmaf(dy, dy, dz*dz));
      if (d < s[15]) topk_insert(s, si, d, __float_as_int(q.w));
    }
  }

  #pragma unroll
  for (int j = 0; j < 16; ++j) spill[j*256 + t] = make_float2(s[j], __int_as_float(si[j]));
  mlp_and_store(lds, spill, t, yat, out, gid);
}

extern "C" void kernel_launch(void* const* d_in, const int* in_sizes, int n_in,
                              void* d_out, int out_size, void* d_ws, size_t ws_size,
                              hipStream_t stream) {
  const float* x   = (const float*)d_in[0];
  const float* y   = (const float*)d_in[1];
  const float* yat = (const float*)d_in[2];
  // d_in[3], d_in[4]: x_batch/y_batch — all zeros, single batch, ignored
  const float* W1  = (const float*)d_in[5];
  const float* b1  = (const float*)d_in[6];
  const float* W2  = (const float*)d_in[7];
  const float* b2  = (const float*)d_in[8];
  const float* W3  = (const float*)d_in[9];
  const float* b3  = (const float*)d_in[10];
  const float* g1  = (const float*)d_in[11];
  const float* be1 = (const float*)d_in[12];
  const float* m1  = (const float*)d_in[13];
  const float* v1  = (const float*)d_in[14];
  const float* g2  = (const float*)d_in[15];
  const float* be2 = (const float*)d_in[16];
  const float* m2  = (const float*)d_in[17];
  const float* v2  = (const float*)d_in[18];
  float* out = (float*)d_out;

  if (ws_size >= 700480) {
    char* ws = (char*)d_ws;
    float4* ys4 = (float4*)(ws);              // M*16 = 320000 B
    int* xorder = (int*)(ws + 320000);        // N*4  = 327680 B
    int* ycnt   = (int*)(ws + 647680);        // 2197*4
    int* xcnt   = (int*)(ws + 656480);        // 2197*4
    int* ystart = (int*)(ws + 665280);        // 2198*4
    int* ycur   = (int*)(ws + 674080);        // 2197*4
    int* xstart = (int*)(ws + 682880);        // 2198*4
    int* xcur   = (int*)(ws + 691680);        // 2197*4  (end 700468)

    zero_kernel<<<18, 256, 0, stream>>>(ycnt, 4400);  // zeroes ycnt+xcnt spans
    hist_kernel<<<(M_PTS+255)/256, 256, 0, stream>>>(y, M_PTS, ycnt);
    hist_kernel<<<(N_PTS+255)/256, 256, 0, stream>>>(x, N_PTS, xcnt);
    scan_kernel<<<1, 1024, 0, stream>>>(ycnt, NCELLS, ystart, ycur);
    scan_kernel<<<1, 1024, 0, stream>>>(xcnt, NCELLS, xstart, xcur);
    scatter_y_kernel<<<(M_PTS+255)/256, 256, 0, stream>>>(y, ycur, ys4);
    sortcell_kernel<<<(NCELLS+255)/256, 256, 0, stream>>>(ys4, ystart);
    scatter_x_kernel<<<(N_PTS+255)/256, 256, 0, stream>>>(x, xcur, xorder);
    knn_mlp_kernel<<<N_PTS/256, 256, 0, stream>>>(x, yat, W1,b1,W2,b2,W3,b3,
        g1,be1,m1,v1, g2,be2,m2,v2, ys4, ystart, xorder, out);
  } else {
    brute_kernel<<<N_PTS/256, 256, 0, stream>>>(x, y, yat, W1,b1,W2,b2,W3,b3,
        g1,be1,m1,v1, g2,be2,m2,v2, out);
  }
}